// Round 10
// baseline (68.943 us; speedup 1.0000x reference)
//
#include <hip/hip_runtime.h>
#include <hip/hip_bf16.h>
#include <math.h>

#define NUM_CLASSES 8192
#define FEAT_DIM    256
#define BATCH       1024
// TEMPERATURE = 0.1 -> logits = dot * 10

typedef long fp8x8;                                  // 8 fp8 in 2 VGPRs
typedef __attribute__((ext_vector_type(4))) float f32x4;

#define GLD16(gp, lp) __builtin_amdgcn_global_load_lds(                       \
    (const __attribute__((address_space(1))) void*)(gp),                      \
    (__attribute__((address_space(3))) void*)(lp), 16, 0, 0)

// ---------------------------------------------------------------------------
// Phase 1: EMA update + fp8 convert, prep-free. One wave per class.
// Block loads all 1024 labels to LDS; each lane keeps 16 in registers;
// per-class ordered match iteration via ballot + ffs (ascending t = batch
// order). Blocks 0..31 also zero rowsum. Saves the prep kernel + CSR traffic.
// ---------------------------------------------------------------------------
__global__ __launch_bounds__(256) void ema_convert_kernel(
    const float* __restrict__ feats, const float* __restrict__ proto,
    const int* __restrict__ labels, unsigned char* __restrict__ P8,
    float* __restrict__ rowsum) {
  __shared__ int lab_s[BATCH];
  const int tid = threadIdx.x;

  ((int4*)lab_s)[tid] = ((const int4*)labels)[tid];   // 256 x 16B = 4 KB
  if (blockIdx.x < 32) rowsum[blockIdx.x * 256 + tid] = 0.0f;
  __syncthreads();

  const int c    = (blockIdx.x << 2) + (tid >> 6);    // class id
  const int lane = tid & 63;

  float4 p = ((const float4*)(proto + (size_t)c * FEAT_DIM))[lane];

  // lane's 16 labels -> match mask for this wave's class
  const int4 L0 = ((const int4*)lab_s)[lane * 4 + 0];
  const int4 L1 = ((const int4*)lab_s)[lane * 4 + 1];
  const int4 L2 = ((const int4*)lab_s)[lane * 4 + 2];
  const int4 L3 = ((const int4*)lab_s)[lane * 4 + 3];
  unsigned m = 0;
  m |= (L0.x == c) << 0;  m |= (L0.y == c) << 1;
  m |= (L0.z == c) << 2;  m |= (L0.w == c) << 3;
  m |= (L1.x == c) << 4;  m |= (L1.y == c) << 5;
  m |= (L1.z == c) << 6;  m |= (L1.w == c) << 7;
  m |= (L2.x == c) << 8;  m |= (L2.y == c) << 9;
  m |= (L2.z == c) << 10; m |= (L2.w == c) << 11;
  m |= (L3.x == c) << 12; m |= (L3.y == c) << 13;
  m |= (L3.z == c) << 14; m |= (L3.w == c) << 15;

  unsigned long long wm = __ballot(m != 0);
  while (wm) {                           // wave-uniform (rare path)
    const int src = __ffsll((long long)wm) - 1;
    unsigned mm = __shfl(m, src);
    while (mm) {
      const int j = __ffs(mm) - 1;
      mm &= mm - 1;
      const int t = src * 16 + j;        // ascending t = batch order
      float4 f = ((const float4*)(feats + (size_t)t * FEAT_DIM))[lane];
      float4 r;
      r.x = 0.5f * p.x + 0.5f * f.x;
      r.y = 0.5f * p.y + 0.5f * f.y;
      r.z = 0.5f * p.z + 0.5f * f.z;
      r.w = 0.5f * p.w + 0.5f * f.w;
      float ss = r.x * r.x + r.y * r.y + r.z * r.z + r.w * r.w;
#pragma unroll
      for (int off = 32; off; off >>= 1) ss += __shfl_xor(ss, off);
      float inv = 1.0f / fmaxf(sqrtf(ss), 1e-12f);
      p.x = r.x * inv; p.y = r.y * inv; p.z = r.z * inv; p.w = r.w * inv;
    }
    wm &= wm - 1;
  }

  int v = __builtin_amdgcn_cvt_pk_fp8_f32(p.x, p.y, 0, false);
  v = __builtin_amdgcn_cvt_pk_fp8_f32(p.z, p.w, v, true);
  ((int*)(P8 + (size_t)c * FEAT_DIM))[lane] = v;
}

// ---------------------------------------------------------------------------
// Phase 2: fused fp8 GEMM (P * P^T / T) -> exp -> mask -> row sums.
// T3+T4 counted-vmcnt pipeline (m218 mechanism): 128x128 tile, BK=128 fp8,
// DOUBLE-BUFFERED 64 KB LDS, 4 chained tasks per block = 8 phases. Steady
// state keeps 16 gload_lds in flight per wave; each phase head waits
// vmcnt(8) (only the current buffer's loads) + raw s_barrier -- NEVER a
// vmcnt(0) drain mid-chain. Buffer overwrite safety: all reads of buf b are
// consumed by MFMAs before the second barrier; the re-stage of b issues
// after it. Epilogues (exp/shuffle/atomics) sit between compute and the
// read-done barrier, hiding in-flight loads; their atomics are FIFO-older
// than the next stage so the vmcnt(8) accounting stays exact.
// Stage geometry byte-identical to the proven conflict-free layout
// (16 x 1KB wave-loads, 16B-chunk XOR pre-swizzle, LROW=128B).
// ---------------------------------------------------------------------------
#define BM 128
#define NB (NUM_CLASSES / BM)           // 64 block-rows
#define NTRI (NB * (NB + 1) / 2)        // 2080 triangular tasks
#define NBLK (NTRI / 4)                 // 520 blocks, 4 tasks each
#define LROW 128                        // bytes per LDS row (128 fp8)

#define WAITV(N)                                                              \
  { asm volatile("s_waitcnt vmcnt(" #N ")" ::: "memory");                     \
    __builtin_amdgcn_sched_barrier(0); }
#define BAR() __builtin_amdgcn_s_barrier()

__global__ __launch_bounds__(256, 2) void gemm_rowsum_kernel(
    const unsigned char* __restrict__ P8, float* __restrict__ rowsum) {
  __shared__ __align__(16) char lds[2][2][BM * LROW];  // [buf][A/B][16KB]=64KB

  // XCD-aware bijective swizzle: 520 = 8 * 65
  const int hw  = blockIdx.x;
  const int bid = (hw & 7) * (NBLK / 8) + (hw >> 3);

  // 4 consecutive triangular tasks
  int bi_[4], bj_[4];
  {
    int rem = bid * 4, bi = 0;
    while (rem >= (NB - bi)) { rem -= (NB - bi); ++bi; }
    int bj = bi + rem;
#pragma unroll
    for (int k = 0; k < 4; ++k) {
      bi_[k] = bi; bj_[k] = bj;
      if (bj + 1 < NB) ++bj; else { ++bi; bj = bi; }
    }
  }

  const int tid  = threadIdx.x;
  const int wid  = tid >> 6;          // 0..3
  const int lane = tid & 63;
  const int wm   = wid >> 1;          // 0..1
  const int wn   = wid & 1;           // 0..1

  f32x4 acc[4][4] = {};

  const int rloc = lane >> 3;             // 0..7 row within 8-row load
  const int csrc = (lane & 7) ^ rloc;     // pre-swizzled source chunk

#define STAGE(T, KT, BUF)                                                     \
  {                                                                           \
    const unsigned char* PA_ = P8 + (size_t)(bi_[T] * BM) * FEAT_DIM;         \
    const unsigned char* PB_ = P8 + (size_t)(bj_[T] * BM) * FEAT_DIM;         \
    _Pragma("unroll")                                                         \
    for (int q = 0; q < 4; ++q) {                                             \
      const int L = wid * 4 + q;          /* 0..15 */                         \
      const int r = L * 8 + rloc;         /* tile row 0..127 */               \
      const size_t go = (size_t)r * FEAT_DIM + (KT) * 128 + csrc * 16;        \
      GLD16(PA_ + go, &lds[BUF][0][L * 1024]);                                \
      GLD16(PB_ + go, &lds[BUF][1][L * 1024]);                                \
    }                                                                         \
  }

  const int g  = lane >> 4;   // 0..3 (k-subslice within the 32-wide MFMA K)
  const int rl = lane & 15;   // 0..15

#define COMPUTE(BUF)                                                          \
  {                                                                           \
    const char* As = &lds[BUF][0][0];                                         \
    const char* Bs = &lds[BUF][1][0];                                         \
    _Pragma("unroll")                                                         \
    for (int kk = 0; kk < 4; ++kk) {                                          \
      const int cl = 2 * kk + (g >> 1);   /* logical 16B chunk */             \
      const int ib = (g & 1) * 8;         /* inner byte */                    \
      fp8x8 a[4], b[4];                                                       \
      _Pragma("unroll")                                                       \
      for (int mi = 0; mi < 4; ++mi) {                                        \
        const int row = wm * 64 + mi * 16 + rl;                               \
        a[mi] = *(const fp8x8*)(As + row * LROW + ((cl ^ (row & 7)) << 4) + ib);\
      }                                                                       \
      _Pragma("unroll")                                                       \
      for (int ni = 0; ni < 4; ++ni) {                                        \
        const int row = wn * 64 + ni * 16 + rl;                               \
        b[ni] = *(const fp8x8*)(Bs + row * LROW + ((cl ^ (row & 7)) << 4) + ib);\
      }                                                                       \
      _Pragma("unroll")                                                       \
      for (int mi = 0; mi < 4; ++mi)                                          \
        _Pragma("unroll")                                                     \
        for (int ni = 0; ni < 4; ++ni)                                        \
          acc[mi][ni] = __builtin_amdgcn_mfma_f32_16x16x32_fp8_fp8(           \
              a[mi], b[ni], acc[mi][ni], 0, 0, 0);                            \
    }                                                                         \
  }

#define EPILOGUE(T)                                                           \
  {                                                                           \
    const int BI = bi_[T], BJ = bj_[T];                                       \
    const bool diag = (BI == BJ);                                             \
    float col[4] = {0.0f, 0.0f, 0.0f, 0.0f};                                  \
    _Pragma("unroll")                                                         \
    for (int mi = 0; mi < 4; ++mi) {                                          \
      const int growb = BI * BM + wm * 64 + mi * 16 + g * 4;                  \
      _Pragma("unroll")                                                       \
      for (int v = 0; v < 4; ++v) {                                           \
        const int grow = growb + v;                                           \
        float rs = 0.0f;                                                      \
        _Pragma("unroll")                                                     \
        for (int ni = 0; ni < 4; ++ni) {                                      \
          const int gcol = BJ * BM + wn * 64 + ni * 16 + rl;                  \
          float e = __expf(10.0f * acc[mi][ni][v]);                           \
          if (diag && grow == gcol) e = 0.0f;                                 \
          rs += e;                                                            \
          col[ni] += e;                                                       \
        }                                                                     \
        rs += __shfl_xor(rs, 1);                                              \
        rs += __shfl_xor(rs, 2);                                              \
        rs += __shfl_xor(rs, 4);                                              \
        rs += __shfl_xor(rs, 8);                                              \
        if (rl == 0) atomicAdd(&rowsum[grow], rs);                            \
      }                                                                       \
    }                                                                         \
    if (!diag) {                                                              \
      _Pragma("unroll")                                                       \
      for (int ni = 0; ni < 4; ++ni) {                                        \
        float cs = col[ni];                                                   \
        cs += __shfl_xor(cs, 16);                                             \
        cs += __shfl_xor(cs, 32);                                             \
        if (g == 0) {                                                         \
          const int gcol = BJ * BM + wn * 64 + ni * 16 + rl;                  \
          atomicAdd(&rowsum[gcol], cs);                                       \
        }                                                                     \
      }                                                                       \
    }                                                                         \
  }

#define ZEROACC()                                                             \
  {                                                                           \
    _Pragma("unroll")                                                         \
    for (int mi = 0; mi < 4; ++mi)                                            \
      _Pragma("unroll")                                                       \
      for (int ni = 0; ni < 4; ++ni)                                          \
        acc[mi][ni] = (f32x4){0.0f, 0.0f, 0.0f, 0.0f};                        \
  }

  // ---- 8-phase counted-vmcnt pipeline: phase p reads buf[p&1] ------------
  STAGE(0, 0, 0);
  STAGE(0, 1, 1);
  // p=0
  WAITV(8); BAR(); COMPUTE(0);              BAR(); STAGE(1, 0, 0);
  // p=1
  WAITV(8); BAR(); COMPUTE(1); EPILOGUE(0); ZEROACC(); BAR(); STAGE(1, 1, 1);
  // p=2
  WAITV(8); BAR(); COMPUTE(0);              BAR(); STAGE(2, 0, 0);
  // p=3
  WAITV(8); BAR(); COMPUTE(1); EPILOGUE(1); ZEROACC(); BAR(); STAGE(2, 1, 1);
  // p=4
  WAITV(8); BAR(); COMPUTE(0);              BAR(); STAGE(3, 0, 0);
  // p=5
  WAITV(8); BAR(); COMPUTE(1); EPILOGUE(2); ZEROACC(); BAR(); STAGE(3, 1, 1);
  // p=6
  WAITV(8); BAR(); COMPUTE(0);              BAR();
  // p=7
  WAITV(0); BAR(); COMPUTE(1); EPILOGUE(3);
}

// ---------------------------------------------------------------------------
// Phase 3: loss = mean(log(rowsum / 8191))
// ---------------------------------------------------------------------------
__global__ __launch_bounds__(256) void finalize_kernel(
    const float* __restrict__ rowsum, float* __restrict__ out) {
  const int tid = threadIdx.x;
  float s = 0.0f;
  for (int i = tid; i < NUM_CLASSES; i += 256) {
    s += logf(rowsum[i] * (1.0f / (float)(NUM_CLASSES - 1)));
  }
#pragma unroll
  for (int off = 32; off; off >>= 1) s += __shfl_xor(s, off);
  __shared__ float red[4];
  if ((tid & 63) == 0) red[tid >> 6] = s;
  __syncthreads();
  if (tid == 0)
    out[0] = (red[0] + red[1] + red[2] + red[3]) * (1.0f / (float)NUM_CLASSES);
}

// ---------------------------------------------------------------------------
extern "C" void kernel_launch(void* const* d_in, const int* in_sizes, int n_in,
                              void* d_out, int out_size, void* d_ws, size_t ws_size,
                              hipStream_t stream) {
  const float* feats  = (const float*)d_in[0];
  const float* proto  = (const float*)d_in[1];
  const int*   labels = (const int*)d_in[2];
  float*       out    = (float*)d_out;

  char* ws = (char*)d_ws;
  unsigned char* P8 = (unsigned char*)ws;                   // 2 MB fp8 P
  float* rowsum = (float*)(ws + (size_t)NUM_CLASSES * FEAT_DIM);

  ema_convert_kernel<<<NUM_CLASSES / 4, 256, 0, stream>>>(feats, proto, labels,
                                                          P8, rowsum);
  gemm_rowsum_kernel<<<NBLK, 256, 0, stream>>>(P8, rowsum);
  finalize_kernel<<<1, 256, 0, stream>>>(rowsum, out);
}

// Round 11
// 61.053 us; speedup vs baseline: 1.1292x; 1.1292x over previous
//
#include <hip/hip_runtime.h>
#include <hip/hip_bf16.h>
#include <math.h>

#define NUM_CLASSES 8192
#define FEAT_DIM    256
#define BATCH       1024
// TEMPERATURE = 0.1 -> logits = dot * 10

typedef long fp8x8;                                  // 8 fp8 in 2 VGPRs
typedef __attribute__((ext_vector_type(4))) float f32x4;

#define GLD16(gp, lp) __builtin_amdgcn_global_load_lds(                       \
    (const __attribute__((address_space(1))) void*)(gp),                      \
    (__attribute__((address_space(3))) void*)(lp), 16, 0, 0)

// ---------------------------------------------------------------------------
// Phase 1: EMA update + fp8 convert, prep-free. One wave per class.
// Block loads all 1024 labels to LDS; each lane keeps 16 in registers;
// per-class ordered match iteration via ballot + ffs (ascending t = batch
// order). Blocks 0..31 also zero rowsum.
// ---------------------------------------------------------------------------
__global__ __launch_bounds__(256) void ema_convert_kernel(
    const float* __restrict__ feats, const float* __restrict__ proto,
    const int* __restrict__ labels, unsigned char* __restrict__ P8,
    float* __restrict__ rowsum) {
  __shared__ int lab_s[BATCH];
  const int tid = threadIdx.x;

  ((int4*)lab_s)[tid] = ((const int4*)labels)[tid];   // 256 x 16B = 4 KB
  if (blockIdx.x < 32) rowsum[blockIdx.x * 256 + tid] = 0.0f;
  __syncthreads();

  const int c    = (blockIdx.x << 2) + (tid >> 6);    // class id
  const int lane = tid & 63;

  float4 p = ((const float4*)(proto + (size_t)c * FEAT_DIM))[lane];

  const int4 L0 = ((const int4*)lab_s)[lane * 4 + 0];
  const int4 L1 = ((const int4*)lab_s)[lane * 4 + 1];
  const int4 L2 = ((const int4*)lab_s)[lane * 4 + 2];
  const int4 L3 = ((const int4*)lab_s)[lane * 4 + 3];
  unsigned m = 0;
  m |= (L0.x == c) << 0;  m |= (L0.y == c) << 1;
  m |= (L0.z == c) << 2;  m |= (L0.w == c) << 3;
  m |= (L1.x == c) << 4;  m |= (L1.y == c) << 5;
  m |= (L1.z == c) << 6;  m |= (L1.w == c) << 7;
  m |= (L2.x == c) << 8;  m |= (L2.y == c) << 9;
  m |= (L2.z == c) << 10; m |= (L2.w == c) << 11;
  m |= (L3.x == c) << 12; m |= (L3.y == c) << 13;
  m |= (L3.z == c) << 14; m |= (L3.w == c) << 15;

  unsigned long long wm = __ballot(m != 0);
  while (wm) {                           // wave-uniform (rare path)
    const int src = __ffsll((long long)wm) - 1;
    unsigned mm = __shfl(m, src);
    while (mm) {
      const int j = __ffs(mm) - 1;
      mm &= mm - 1;
      const int t = src * 16 + j;        // ascending t = batch order
      float4 f = ((const float4*)(feats + (size_t)t * FEAT_DIM))[lane];
      float4 r;
      r.x = 0.5f * p.x + 0.5f * f.x;
      r.y = 0.5f * p.y + 0.5f * f.y;
      r.z = 0.5f * p.z + 0.5f * f.z;
      r.w = 0.5f * p.w + 0.5f * f.w;
      float ss = r.x * r.x + r.y * r.y + r.z * r.z + r.w * r.w;
#pragma unroll
      for (int off = 32; off; off >>= 1) ss += __shfl_xor(ss, off);
      float inv = 1.0f / fmaxf(sqrtf(ss), 1e-12f);
      p.x = r.x * inv; p.y = r.y * inv; p.z = r.z * inv; p.w = r.w * inv;
    }
    wm &= wm - 1;
  }

  int v = __builtin_amdgcn_cvt_pk_fp8_f32(p.x, p.y, 0, false);
  v = __builtin_amdgcn_cvt_pk_fp8_f32(p.z, p.w, v, true);
  ((int*)(P8 + (size_t)c * FEAT_DIM))[lane] = v;
}

// ---------------------------------------------------------------------------
// Phase 2: fused fp8 GEMM (P * P^T / T) -> exp -> mask -> row sums.
// R9's proven skeleton (128x128 tile, BK=128 fp8, single 32 KB buffer,
// 2 barriers/phase, 2-task chains, grid 1040 mostly co-resident) with ONE
// change: in-chain epilogues write reduced partials to a 4 KB LDS scratch
// (ds_write, drained in ~120 cy by lgkm) instead of device atomics; ALL
// global atomicAdds are deferred to a single flush AFTER the last barrier
// of the block, so no vmcnt drain ever waits on a contended far-RMW
// (the R8-R10 hidden cost). LDS 36 KB -> still 4 blocks/CU.
// ---------------------------------------------------------------------------
#define BM 128
#define NB (NUM_CLASSES / BM)           // 64 block-rows
#define NTRI (NB * (NB + 1) / 2)        // 2080 triangular tasks
#define NBLK (NTRI / 2)                 // 1040 blocks, 2 tasks each
#define LROW 128                        // bytes per LDS row (128 fp8)

__global__ __launch_bounds__(256, 4) void gemm_rowsum_kernel(
    const unsigned char* __restrict__ P8, float* __restrict__ rowsum) {
  __shared__ __align__(16) char As[BM * LROW];  // 16 KB
  __shared__ __align__(16) char Bs[BM * LROW];  // 16 KB
  __shared__ float Lrow[2][2][BM];              // [task][wn][row]  2 KB
  __shared__ float Lcol[2][2][BM];              // [task][wm][col]  2 KB

  // XCD-aware bijective swizzle: 1040 = 8 * 130
  const int hw  = blockIdx.x;
  const int bid = (hw & 7) * (NBLK / 8) + (hw >> 3);

  // task0 = 2*bid -> (bi0, bj0); task1 = next triangular task
  int rem = bid * 2, bi0 = 0;
  while (rem >= (NB - bi0)) { rem -= (NB - bi0); ++bi0; }
  const int bj0 = bi0 + rem;
  const int bi1 = (bj0 + 1 < NB) ? bi0 : bi0 + 1;
  const int bj1 = (bj0 + 1 < NB) ? bj0 + 1 : bi0 + 1;

  const int tid  = threadIdx.x;
  const int wid  = tid >> 6;          // 0..3
  const int lane = tid & 63;
  const int wm   = wid >> 1;          // 0..1
  const int wn   = wid & 1;           // 0..1

  f32x4 acc[4][4] = {};

  const int rloc = lane >> 3;             // 0..7 row within 8-row load
  const int csrc = (lane & 7) ^ rloc;     // pre-swizzled source chunk
  const unsigned char* PA = P8 + (size_t)(bi0 * BM) * FEAT_DIM;
  const unsigned char* PB = P8 + (size_t)(bj0 * BM) * FEAT_DIM;

#define STAGE(kt)                                                             \
  {                                                                           \
    _Pragma("unroll")                                                         \
    for (int q = 0; q < 4; ++q) {                                             \
      const int L = wid * 4 + q;          /* 0..15 */                         \
      const int r = L * 8 + rloc;         /* tile row 0..127 */               \
      const size_t go = (size_t)r * FEAT_DIM + (kt) * 128 + csrc * 16;        \
      GLD16(PA + go, As + L * 1024);                                          \
      GLD16(PB + go, Bs + L * 1024);                                          \
    }                                                                         \
  }

  const int g  = lane >> 4;   // 0..3
  const int rl = lane & 15;   // 0..15

#define COMPUTE()                                                             \
  {                                                                           \
    _Pragma("unroll")                                                         \
    for (int kk = 0; kk < 4; ++kk) {                                          \
      const int cl = 2 * kk + (g >> 1);   /* logical 16B chunk */             \
      const int ib = (g & 1) * 8;         /* inner byte */                    \
      fp8x8 a[4], b[4];                                                       \
      _Pragma("unroll")                                                       \
      for (int mi = 0; mi < 4; ++mi) {                                        \
        const int row = wm * 64 + mi * 16 + rl;                               \
        a[mi] = *(const fp8x8*)(As + row * LROW + ((cl ^ (row & 7)) << 4) + ib);\
      }                                                                       \
      _Pragma("unroll")                                                       \
      for (int ni = 0; ni < 4; ++ni) {                                        \
        const int row = wn * 64 + ni * 16 + rl;                               \
        b[ni] = *(const fp8x8*)(Bs + row * LROW + ((cl ^ (row & 7)) << 4) + ib);\
      }                                                                       \
      _Pragma("unroll")                                                       \
      for (int mi = 0; mi < 4; ++mi)                                          \
        _Pragma("unroll")                                                     \
        for (int ni = 0; ni < 4; ++ni)                                        \
          acc[mi][ni] = __builtin_amdgcn_mfma_f32_16x16x32_fp8_fp8(           \
              a[mi], b[ni], acc[mi][ni], 0, 0, 0);                            \
    }                                                                         \
  }

  // Epilogue calc: exp + reduce, partials -> LDS (no global atomics here).
#define EPI_CALC(T, BI, BJ)                                                   \
  {                                                                           \
    const bool diag = ((BI) == (BJ));                                         \
    float col[4] = {0.0f, 0.0f, 0.0f, 0.0f};                                  \
    _Pragma("unroll")                                                         \
    for (int mi = 0; mi < 4; ++mi) {                                          \
      _Pragma("unroll")                                                       \
      for (int v = 0; v < 4; ++v) {                                           \
        const int lrow = wm * 64 + mi * 16 + g * 4 + v;                       \
        const int grow = (BI) * BM + lrow;                                    \
        float rs = 0.0f;                                                      \
        _Pragma("unroll")                                                     \
        for (int ni = 0; ni < 4; ++ni) {                                      \
          const int gcol = (BJ) * BM + wn * 64 + ni * 16 + rl;                \
          float e = __expf(10.0f * acc[mi][ni][v]);                           \
          if (diag && grow == gcol) e = 0.0f;                                 \
          rs += e;                                                            \
          col[ni] += e;                                                       \
        }                                                                     \
        rs += __shfl_xor(rs, 1);                                              \
        rs += __shfl_xor(rs, 2);                                              \
        rs += __shfl_xor(rs, 4);                                              \
        rs += __shfl_xor(rs, 8);                                              \
        if (rl == 0) Lrow[T][wn][lrow] = rs;                                  \
      }                                                                       \
    }                                                                         \
    _Pragma("unroll")                                                         \
    for (int ni = 0; ni < 4; ++ni) {                                          \
      float cs = col[ni];                                                     \
      cs += __shfl_xor(cs, 16);                                               \
      cs += __shfl_xor(cs, 32);                                               \
      if (g == 0) Lcol[T][wm][wn * 64 + ni * 16 + rl] = cs;                   \
    }                                                                         \
  }

#define ZEROACC()                                                             \
  {                                                                           \
    _Pragma("unroll")                                                         \
    for (int mi = 0; mi < 4; ++mi)                                            \
      _Pragma("unroll")                                                       \
      for (int ni = 0; ni < 4; ++ni)                                          \
        acc[mi][ni] = (f32x4){0.0f, 0.0f, 0.0f, 0.0f};                        \
  }

  // ---- R9 chain: 4 phases, 2 barriers each ------------------------------
  STAGE(0);
  __syncthreads();                       // (task0,kt0) landed

  // p0
  COMPUTE();
  __syncthreads();
  STAGE(1);
  __syncthreads();
  // p1 (task switch)
  COMPUTE();
  __syncthreads();
  PA = P8 + (size_t)(bi1 * BM) * FEAT_DIM;
  PB = P8 + (size_t)(bj1 * BM) * FEAT_DIM;
  STAGE(0);
  EPI_CALC(0, bi0, bj0);                 // hides the staging drain; LDS only
  ZEROACC();
  __syncthreads();
  // p2
  COMPUTE();
  __syncthreads();
  STAGE(1);
  __syncthreads();
  // p3
  COMPUTE();
  EPI_CALC(1, bi1, bj1);
  __syncthreads();                       // LDS partials visible (lgkm only)

  // ---- single deferred flush: atomics issued once, never drained --------
  {
    const int T = tid >> 7;              // 0..1  (task)
    const int r = tid & 127;             // row / col slot
    const int biT = T ? bi1 : bi0;
    const int bjT = T ? bj1 : bj0;
    atomicAdd(&rowsum[biT * BM + r], Lrow[T][0][r] + Lrow[T][1][r]);
    if (biT != bjT)
      atomicAdd(&rowsum[bjT * BM + r], Lcol[T][0][r] + Lcol[T][1][r]);
  }
}

// ---------------------------------------------------------------------------
// Phase 3: loss = mean(log(rowsum / 8191))
// ---------------------------------------------------------------------------
__global__ __launch_bounds__(256) void finalize_kernel(
    const float* __restrict__ rowsum, float* __restrict__ out) {
  const int tid = threadIdx.x;
  float s = 0.0f;
  for (int i = tid; i < NUM_CLASSES; i += 256) {
    s += logf(rowsum[i] * (1.0f / (float)(NUM_CLASSES - 1)));
  }
#pragma unroll
  for (int off = 32; off; off >>= 1) s += __shfl_xor(s, off);
  __shared__ float red[4];
  if ((tid & 63) == 0) red[tid >> 6] = s;
  __syncthreads();
  if (tid == 0)
    out[0] = (red[0] + red[1] + red[2] + red[3]) * (1.0f / (float)NUM_CLASSES);
}

// ---------------------------------------------------------------------------
extern "C" void kernel_launch(void* const* d_in, const int* in_sizes, int n_in,
                              void* d_out, int out_size, void* d_ws, size_t ws_size,
                              hipStream_t stream) {
  const float* feats  = (const float*)d_in[0];
  const float* proto  = (const float*)d_in[1];
  const int*   labels = (const int*)d_in[2];
  float*       out    = (float*)d_out;

  char* ws = (char*)d_ws;
  unsigned char* P8 = (unsigned char*)ws;                   // 2 MB fp8 P
  float* rowsum = (float*)(ws + (size_t)NUM_CLASSES * FEAT_DIM);

  ema_convert_kernel<<<NUM_CLASSES / 4, 256, 0, stream>>>(feats, proto, labels,
                                                          P8, rowsum);
  gemm_rowsum_kernel<<<NBLK, 256, 0, stream>>>(P8, rowsum);
  finalize_kernel<<<1, 256, 0, stream>>>(rowsum, out);
}